// Round 4
// baseline (5361.735 us; speedup 1.0000x reference)
//
#include <hip/hip_runtime.h>

#define Cn 16
#define Dn 96
#define Sn (Dn*Dn*Dn)        /* 884736 */
#define DSTRIDE (Dn*Dn)      /* 9216 */
#define ENC_NEG_INF 0x007FFFFFu

typedef float v2f __attribute__((ext_vector_type(2)));
typedef float v4f __attribute__((ext_vector_type(4)));
typedef _Float16 v4h __attribute__((ext_vector_type(4)));

__device__ __forceinline__ v2f ld2(const float* p){
    v2f r; __builtin_memcpy(&r, p, 8); return r;
}
// monotonic float<->uint map for atomicMax on signed floats
__device__ __forceinline__ unsigned encf(float f){
    unsigned u = __float_as_uint(f);
    return (u & 0x80000000u) ? ~u : (u | 0x80000000u);
}
__device__ __forceinline__ float decf(unsigned u){
    return (u & 0x80000000u) ? __uint_as_float(u ^ 0x80000000u) : __uint_as_float(~u);
}
// tanh(x) = 1 - 2/(exp(2x)+1)
__device__ __forceinline__ float ftanh(float x){
    float t = __expf(2.0f*x);
    return 1.0f - __fdividef(2.0f, t + 1.0f);
}
__device__ __forceinline__ int clampi(int v){ return v<0?0:(v>Dn-1?Dn-1:v); }

__global__ void init_kernel(unsigned* __restrict__ maxv){
    if (threadIdx.x < 16) maxv[threadIdx.x] = ENC_NEG_INF;
}

// Stencil weight reorder (once):
//  wpW[(t*3+q)*16+c] = wp[(3c+q)*27+t]  (lane loads dwordx4 at c=4lg)
//  bpP[q*16+c] = bp[3c+q]
__global__ void tr_kernel(const float* __restrict__ wp, const float* __restrict__ bp,
                          float* __restrict__ wpW, float* __restrict__ bpP){
    const int i = blockIdx.x*256 + threadIdx.x;
    if (i < 1296){ const int c=i&15, tq=i>>4, q=tq%3, t=tq/3; wpW[i] = wp[(3*c+q)*27 + t]; }
    if (i < 48)  { const int q=i>>4, c=i&15; bpP[i] = bp[3*c + q]; }
}

// Pack MLP weights as MFMA *A*-fragments (M=out-feature, K=in-feature),
// split hi/lo f16 (3-term split-f16 GEMM ~ fp32 accuracy).
// A-frag tile (mt,ks): lane l elem e holds A[m=16mt+(l&15)][k=16ks+4*(l>>4)+e].
// Layer-1 k runs over the PERMUTED dwconv index j=q*16+c (orig = 3c+q), q=ks.
__global__ void pack_kernel(const float* __restrict__ w1, const float* __restrict__ w2,
                            const float* __restrict__ w3,
                            _Float16* __restrict__ w1Ah, _Float16* __restrict__ w1Al,
                            _Float16* __restrict__ w2Ah, _Float16* __restrict__ w2Al,
                            _Float16* __restrict__ w3Ah, _Float16* __restrict__ w3Al){
    const int i = blockIdx.x*256 + threadIdx.x;
    const int e = i & 3, l = (i>>2) & 63, tile = i >> 8;
    const int lr = l & 15, lg = l >> 4;
    if (i < 3072){ // w1 [64 out x 48 in], tiles = mt*3+ks
        const int ks = tile % 3, mt = tile / 3;
        const int c = 4*lg + e;                       // k = 16ks + 4lg + e -> q=ks, c
        const float v = w1[(16*mt + lr)*48 + 3*c + ks];
        const _Float16 hh = (_Float16)v;
        w1Ah[i] = hh; w1Al[i] = (_Float16)(v - (float)hh);
    }
    if (i < 4096){ // w2 [64 x 64], tiles = mt*4+ks
        const int ks = tile & 3, mt = tile >> 2;
        const float v = w2[(16*mt + lr)*64 + 16*ks + 4*lg + e];
        const _Float16 hh = (_Float16)v;
        w2Ah[i] = hh; w2Al[i] = (_Float16)(v - (float)hh);
    }
    if (i < 1024){ // w3 [16 x 64], tiles = ks
        const int ks = tile;
        const float v = w3[lr*64 + 16*ks + 4*lg + e];
        const _Float16 hh = (_Float16)v;
        w3Ah[i] = hh; w3Al[i] = (_Float16)(v - (float)hh);
    }
}

// global max of x0 ch3 -> slot; initial mask (u8) all-ones
__global__ __launch_bounds__(256) void prep_kernel(const float* __restrict__ x3,
    unsigned char* __restrict__ maskA, unsigned* __restrict__ slot)
{
    const int idx = blockIdx.x*256 + threadIdx.x;
    maskA[idx] = 1;
    float v = x3[idx];
    #pragma unroll
    for (int o=32;o;o>>=1) v = fmaxf(v, __shfl_down(v, o));
    __shared__ float red[4];
    const int lane = threadIdx.x & 63, wid = threadIdx.x >> 6;
    if (lane==0) red[wid]=v;
    __syncthreads();
    if (threadIdx.x==0){
        float m = fmaxf(fmaxf(red[0],red[1]), fmaxf(red[2],red[3]));
        atomicMax(slot, encf(m));
    }
}

// one-time transpose x0 [16][Sn] -> xT [Sn][16] (voxel-major)
__global__ __launch_bounds__(256) void transpose_kernel(const float* __restrict__ x,
    float* __restrict__ xT)
{
    const int idx = blockIdx.x*256 + threadIdx.x;
    float v[16];
    #pragma unroll
    for (int c=0;c<16;++c) v[c] = x[(size_t)c*Sn + idx];
    float* dst = xT + (size_t)idx*16;
    #pragma unroll
    for (int k=0;k<4;++k){
        v4f t = {v[4*k], v[4*k+1], v[4*k+2], v[4*k+3]};
        __builtin_memcpy(dst + 4*k, &t, 16);
    }
}

// fused: masked stencil dwconv -> MLP 48->64->64->16, ALL fragments born in
// registers (voxels = N dim, weights = A operand): C-frag[m=4lg+r][n=lr] feeds
// next B-frag[k=4lg+e][n=lr] directly. ZERO LDS, zero barriers.
// Lane (lr,lg) owns voxels {w0+16j} channels {4lg..4lg+3}; x loads are
// dwordx4 with 16B/lane, 64 lanes = 1KB contiguous (perfect coalescing).
// Two row-passes (2 voxel-groups each) keep peak VGPR ~130.
__global__ __launch_bounds__(256, 3) void update_kernel(
    const float* __restrict__ xinT, const unsigned char* __restrict__ min_,
    float* __restrict__ xout, const int final_, float* __restrict__ x3out,
    const float* __restrict__ wpW, const float* __restrict__ bpP,
    const _Float16* __restrict__ w1Ah, const _Float16* __restrict__ w1Al,
    const float* __restrict__ b1,
    const _Float16* __restrict__ w2Ah, const _Float16* __restrict__ w2Al,
    const float* __restrict__ b2,
    const _Float16* __restrict__ w3Ah, const _Float16* __restrict__ w3Al,
    const float* __restrict__ b3,
    unsigned* __restrict__ slot_post)
{
    const int tid  = threadIdx.x;
    const int lane = tid & 63, wv = tid >> 6;
    const int lr   = lane & 15, lg = lane >> 4;
    const int wbase = blockIdx.x*32;
    const int d = blockIdx.z;
    const int w0 = wbase + lr;
    float vmax = -INFINITY;

    #pragma unroll 1
    for (int pass=0; pass<2; ++pass){
        const int h = blockIdx.y*8 + 2*wv + pass;

        // ---------------- stencil dwconv (fp32 VALU) -----------------------
        v2f pacc[2][3][2];
        #pragma unroll
        for (int j=0;j<2;++j)
            #pragma unroll
            for (int q=0;q<3;++q)
                #pragma unroll
                for (int pr=0;pr<2;++pr)
                    pacc[j][q][pr] = ld2(bpP + q*16 + 4*lg + 2*pr);

        #pragma unroll 1
        for (int dz=-1; dz<=1; ++dz){
            const int zz = d+dz, zc = clampi(zz);
            const int vz = (zz==zc);
            #pragma unroll
            for (int dy=-1; dy<=1; ++dy){
                const int yy = h+dy, yc = clampi(yy);
                const int vzy = vz & (yy==yc);
                const int rbase = zc*DSTRIDE + yc*Dn;
                #pragma unroll
                for (int dx=-1; dx<=1; ++dx){
                    const int t = (dz+1)*9 + (dy+1)*3 + (dx+1);
                    v4f wq[3];
                    #pragma unroll
                    for (int q=0;q<3;++q)
                        __builtin_memcpy(&wq[q], wpW + (t*3+q)*16 + 4*lg, 16);
                    #pragma unroll
                    for (int j=0;j<2;++j){
                        const int xx = w0 + 16*j + dx;
                        const int xc = clampi(xx);
                        const int noff = rbase + xc;
                        const float m = (vzy & (xx==xc)) ? (float)min_[noff] : 0.0f;
                        v4f xv; __builtin_memcpy(&xv, xinT + (size_t)noff*16 + 4*lg, 16);
                        const v2f m2 = {m, m};
                        const v2f x0m = (v2f){xv[0], xv[1]} * m2;
                        const v2f x1m = (v2f){xv[2], xv[3]} * m2;
                        #pragma unroll
                        for (int q=0;q<3;++q){
                            pacc[j][q][0] = __builtin_elementwise_fma((v2f){wq[q][0],wq[q][1]}, x0m, pacc[j][q][0]);
                            pacc[j][q][1] = __builtin_elementwise_fma((v2f){wq[q][2],wq[q][3]}, x1m, pacc[j][q][1]);
                        }
                    }
                }
            }
        }

        // center x + mask for residual
        const int idx0 = d*DSTRIDE + h*Dn + w0;
        v4f ctr[2]; float mctr[2];
        #pragma unroll
        for (int j=0;j<2;++j){
            __builtin_memcpy(&ctr[j], xinT + (size_t)(idx0+16*j)*16 + 4*lg, 16);
            mctr[j] = (float)min_[idx0+16*j];
        }

        // -------- B1 frags (split hi/lo) from dwconv accumulators ----------
        v4h b1h[2][3], b1l[2][3];
        #pragma unroll
        for (int j=0;j<2;++j)
            #pragma unroll
            for (int q=0;q<3;++q){
                const float f0=pacc[j][q][0].x, f1=pacc[j][q][0].y;
                const float f2=pacc[j][q][1].x, f3v=pacc[j][q][1].y;
                v4h hi = {(_Float16)f0,(_Float16)f1,(_Float16)f2,(_Float16)f3v};
                v4h lo = {(_Float16)(f0-(float)hi[0]), (_Float16)(f1-(float)hi[1]),
                          (_Float16)(f2-(float)hi[2]), (_Float16)(f3v-(float)hi[3])};
                b1h[j][q]=hi; b1l[j][q]=lo;
            }

        // -------- GEMM1: c1[mt][j] = W1 @ p + b1 ---------------------------
        v4f c1[4][2];
        #pragma unroll
        for (int mt=0;mt<4;++mt){
            v4f bb; __builtin_memcpy(&bb, b1 + 16*mt + 4*lg, 16);
            c1[mt][0]=bb; c1[mt][1]=bb;
        }
        #pragma unroll
        for (int ks=0;ks<3;++ks)
            #pragma unroll
            for (int mt=0;mt<4;++mt){
                v4h ah, al;
                __builtin_memcpy(&ah, w1Ah + ((mt*3+ks)*64 + lane)*4, 8);
                __builtin_memcpy(&al, w1Al + ((mt*3+ks)*64 + lane)*4, 8);
                #pragma unroll
                for (int j=0;j<2;++j){
                    c1[mt][j] = __builtin_amdgcn_mfma_f32_16x16x16f16(ah, b1h[j][ks], c1[mt][j],0,0,0);
                    c1[mt][j] = __builtin_amdgcn_mfma_f32_16x16x16f16(al, b1h[j][ks], c1[mt][j],0,0,0);
                    c1[mt][j] = __builtin_amdgcn_mfma_f32_16x16x16f16(ah, b1l[j][ks], c1[mt][j],0,0,0);
                }
            }

        // -------- GEMM2: c2[mt][j] = W2 @ tanh(c1) + b2 --------------------
        v4f c2[4][2];
        #pragma unroll
        for (int mt=0;mt<4;++mt){
            v4f bb; __builtin_memcpy(&bb, b2 + 16*mt + 4*lg, 16);
            c2[mt][0]=bb; c2[mt][1]=bb;
        }
        #pragma unroll
        for (int ks=0;ks<4;++ks){
            v4h b2h[2], b2l[2];
            #pragma unroll
            for (int j=0;j<2;++j){
                float t0=ftanh(c1[ks][j][0]), t1=ftanh(c1[ks][j][1]);
                float t2=ftanh(c1[ks][j][2]), t3=ftanh(c1[ks][j][3]);
                v4h hi = {(_Float16)t0,(_Float16)t1,(_Float16)t2,(_Float16)t3};
                v4h lo = {(_Float16)(t0-(float)hi[0]), (_Float16)(t1-(float)hi[1]),
                          (_Float16)(t2-(float)hi[2]), (_Float16)(t3-(float)hi[3])};
                b2h[j]=hi; b2l[j]=lo;
            }
            #pragma unroll
            for (int mt=0;mt<4;++mt){
                v4h ah, al;
                __builtin_memcpy(&ah, w2Ah + ((mt*4+ks)*64 + lane)*4, 8);
                __builtin_memcpy(&al, w2Al + ((mt*4+ks)*64 + lane)*4, 8);
                #pragma unroll
                for (int j=0;j<2;++j){
                    c2[mt][j] = __builtin_amdgcn_mfma_f32_16x16x16f16(ah, b2h[j], c2[mt][j],0,0,0);
                    c2[mt][j] = __builtin_amdgcn_mfma_f32_16x16x16f16(al, b2h[j], c2[mt][j],0,0,0);
                    c2[mt][j] = __builtin_amdgcn_mfma_f32_16x16x16f16(ah, b2l[j], c2[mt][j],0,0,0);
                }
            }
        }

        // -------- GEMM3: c3[j] = W3 @ tanh(c2) + b3 ------------------------
        v4f c3[2];
        {
            v4f bb; __builtin_memcpy(&bb, b3 + 4*lg, 16);
            c3[0]=bb; c3[1]=bb;
        }
        #pragma unroll
        for (int ks=0;ks<4;++ks){
            v4h b3h[2], b3l[2];
            #pragma unroll
            for (int j=0;j<2;++j){
                float t0=ftanh(c2[ks][j][0]), t1=ftanh(c2[ks][j][1]);
                float t2=ftanh(c2[ks][j][2]), t3=ftanh(c2[ks][j][3]);
                v4h hi = {(_Float16)t0,(_Float16)t1,(_Float16)t2,(_Float16)t3};
                v4h lo = {(_Float16)(t0-(float)hi[0]), (_Float16)(t1-(float)hi[1]),
                          (_Float16)(t2-(float)hi[2]), (_Float16)(t3-(float)hi[3])};
                b3h[j]=hi; b3l[j]=lo;
            }
            v4h ah, al;
            __builtin_memcpy(&ah, w3Ah + (ks*64 + lane)*4, 8);
            __builtin_memcpy(&al, w3Al + (ks*64 + lane)*4, 8);
            #pragma unroll
            for (int j=0;j<2;++j){
                c3[j] = __builtin_amdgcn_mfma_f32_16x16x16f16(ah, b3h[j], c3[j],0,0,0);
                c3[j] = __builtin_amdgcn_mfma_f32_16x16x16f16(al, b3h[j], c3[j],0,0,0);
                c3[j] = __builtin_amdgcn_mfma_f32_16x16x16f16(ah, b3l[j], c3[j],0,0,0);
            }
        }

        // -------- residual + store (+ ch3 plane & max) ---------------------
        #pragma unroll
        for (int j=0;j<2;++j){
            const int vox = idx0 + 16*j;
            v4f xn;
            #pragma unroll
            for (int r=0;r<4;++r) xn[r] = fmaf(ctr[j][r], mctr[j], c3[j][r]);
            if (!final_){
                __builtin_memcpy(xout + (size_t)vox*16 + 4*lg, &xn, 16);
            } else {
                #pragma unroll
                for (int r=0;r<4;++r) xout[(size_t)(4*lg+r)*Sn + vox] = xn[r];
            }
            if (lg==0){
                if (x3out) x3out[vox] = xn[3];
                vmax = fmaxf(vmax, xn[3]);
            }
        }
    }

    #pragma unroll
    for (int o=32;o;o>>=1) vmax = fmaxf(vmax, __shfl_down(vmax, o));
    if (lane==0) atomicMax(slot_post, encf(vmax));
}

// alive0 from masked old ch3, alive1 from unmasked new ch3; sources are
// contiguous planes (a*_t=0) or voxel-major strided (a*_t=1, ws fallback).
__global__ __launch_bounds__(256) void mask_kernel(
    const float* __restrict__ a0src, const int a0_t,
    const unsigned char* __restrict__ min_,
    const float* __restrict__ a1src, const int a1_t,
    unsigned char* __restrict__ mout,
    const unsigned* __restrict__ slot_pre, const unsigned* __restrict__ slot_post,
    unsigned* __restrict__ slot_next)
{
    const int idx = blockIdx.x*256 + threadIdx.x;
    const int w = idx % Dn;
    const int h = (idx / Dn) % Dn;
    const int d = idx / DSTRIDE;
    const float th0 = 0.1f * decf(*slot_pre);
    const float th1 = 0.1f * decf(*slot_post);
    float a0 = -INFINITY, a1 = -INFINITY;
    #pragma unroll
    for (int t=0;t<27;++t){
        const int dz=t/9-1, dy=(t/3)%3-1, dx=t%3-1;
        const int zz=d+dz, yy=h+dy, xx=w+dx;
        if ((unsigned)zz<(unsigned)Dn && (unsigned)yy<(unsigned)Dn &&
            (unsigned)xx<(unsigned)Dn){
            const int noff = idx + dz*DSTRIDE + dy*Dn + dx;
            const float x0v = a0_t ? a0src[(size_t)noff*16+3] : a0src[noff];
            const float x1v = a1_t ? a1src[(size_t)noff*16+3] : a1src[noff];
            a0 = fmaxf(a0, x0v * (float)min_[noff]);
            a1 = fmaxf(a1, x1v);
        }
    }
    const bool life = (a0 > th0) && (a1 > th1) && !(d==Dn-1 && h>=48);
    mout[idx] = life ? 1 : 0;
    const float mv = life ? 1.0f : 0.0f;

    const float xv3 = a1_t ? a1src[(size_t)idx*16+3] : a1src[idx];
    float f3 = xv3*mv;   // final ch3 value -> pre-max of next step
    #pragma unroll
    for (int o=32;o;o>>=1) f3 = fmaxf(f3, __shfl_down(f3, o));
    __shared__ float red[4];
    const int lane = threadIdx.x & 63, wid = threadIdx.x >> 6;
    if (lane==0) red[wid]=f3;
    __syncthreads();
    if (threadIdx.x==0){
        float m = fmaxf(fmaxf(red[0],red[1]), fmaxf(red[2],red[3]));
        atomicMax(slot_next, encf(m));
    }
}

// final: apply last step's mask in place on d_out (channel-major)
__global__ __launch_bounds__(256) void apply_kernel(float* __restrict__ x,
    const unsigned char* __restrict__ mk)
{
    const int idx = blockIdx.x*256 + threadIdx.x;
    const float m = (float)mk[idx];
    #pragma unroll
    for (int c=0;c<Cn;++c) x[(size_t)c*Sn+idx] *= m;
}

extern "C" void kernel_launch(void* const* d_in, const int* in_sizes, int n_in,
                              void* d_out, int out_size, void* d_ws, size_t ws_size,
                              hipStream_t stream)
{
    const float* x0 = (const float*)d_in[0];
    const float* wp = (const float*)d_in[1];
    const float* bp = (const float*)d_in[2];
    const float* w1 = (const float*)d_in[3];
    const float* b1 = (const float*)d_in[4];
    const float* w2 = (const float*)d_in[5];
    const float* b2 = (const float*)d_in[6];
    const float* w3 = (const float*)d_in[7];
    const float* b3 = (const float*)d_in[8];
    float* out = (float*)d_out;

    // ws: T0 16*Sn f32 | maskA,maskB u8 Sn each | maxv | wpW 1296 f | bpP 48 f |
    //     A-frag packs 16384 h | [P0,P1 ch3 planes Sn f32 each, if ws allows]
    float* T0 = (float*)d_ws;
    unsigned char* mA = (unsigned char*)(T0 + (size_t)Cn*Sn);
    unsigned char* mB = mA + Sn;
    unsigned* maxv = (unsigned*)(mB + Sn);
    float* wpW = (float*)(maxv + 16);
    float* bpP = wpW + 1296;
    _Float16* w1Ah = (_Float16*)(bpP + 48);
    _Float16* w1Al = w1Ah + 3072;
    _Float16* w2Ah = w1Al + 3072;
    _Float16* w2Al = w2Ah + 4096;
    _Float16* w3Ah = w2Al + 4096;
    _Float16* w3Al = w3Ah + 1024;
    float* Pbase = (float*)(w3Al + 1024);
    const size_t need = (size_t)((char*)(Pbase + 2*(size_t)Sn) - (char*)d_ws);
    const bool planes = (ws_size >= need);
    float* P[2] = { Pbase, Pbase + Sn };
    float* T1 = out;   // d_out doubles as the second voxel-major state buffer

    init_kernel<<<1, 64, 0, stream>>>(maxv);
    tr_kernel<<<6, 256, 0, stream>>>(wp, bp, wpW, bpP);
    pack_kernel<<<16, 256, 0, stream>>>(w1, w2, w3, w1Ah, w1Al, w2Ah, w2Al, w3Ah, w3Al);
    prep_kernel<<<Sn/256, 256, 0, stream>>>(x0 + (size_t)3*Sn, mA, &maxv[0]);
    transpose_kernel<<<Sn/256, 256, 0, stream>>>(x0, T1);

    // steps 0-2 ping-pong voxel-major between T1(d_out) and T0(ws);
    // step 3 reads T0, writes channel-major to d_out.
    const float* xiT[4] = {T1, T0, T1, T0};
    float*       xo[4]  = {T0, T1, T0, out};
    const int    fin[4] = {0, 0, 0, 1};
    const unsigned char* mi[4] = {mA, mB, mA, mB};
    unsigned char*       mo[4] = {mB, mA, mB, mA};

    dim3 ugrid(Dn/32, Dn/8, Dn);
    for (int s=0; s<4; ++s){
        float* x3o = (planes && s<3) ? P[s&1] : nullptr;
        update_kernel<<<ugrid, 256, 0, stream>>>(xiT[s], mi[s], xo[s], fin[s], x3o,
            wpW, bpP, w1Ah, w1Al, b1, w2Ah, w2Al, b2, w3Ah, w3Al, b3, &maxv[2*s+1]);

        const float* a0src; int a0t;
        if (s==0){ a0src = x0 + (size_t)3*Sn; a0t = 0; }
        else if (planes){ a0src = P[(s-1)&1]; a0t = 0; }
        else { a0src = xiT[s]; a0t = 1; }
        const float* a1src; int a1t;
        if (s==3){ a1src = out + (size_t)3*Sn; a1t = 0; }
        else if (planes){ a1src = P[s&1]; a1t = 0; }
        else { a1src = xo[s]; a1t = 1; }

        mask_kernel<<<Sn/256, 256, 0, stream>>>(a0src, a0t, mi[s], a1src, a1t,
            mo[s], &maxv[2*s], &maxv[2*s+1], &maxv[2*s+2]);
    }
    apply_kernel<<<Sn/256, 256, 0, stream>>>(out, mA);
}